// Round 1
// baseline (4073.647 us; speedup 1.0000x reference)
//
#include <hip/hip_runtime.h>

// RNN on MI355X: h_{t+1} = tanh(table[X[:,t]] + h_t @ W_hh), 256 steps, B=1024, H=512.
// Strategy: batch-partition (16 rows/block, 64 blocks, no inter-block sync),
// bf16 MFMA 16x16x32 with 2-term split (h_hi + h_lo) @ bf16(W_hh).

typedef __attribute__((ext_vector_type(8))) short short8;
typedef __attribute__((ext_vector_type(4))) float f32x4;

#define B_ 1024
#define T_ 256
#define E_ 128
#define H_ 512
#define V_ 115

__device__ inline short f32_to_bf16(float f) {
  unsigned u = __builtin_bit_cast(unsigned, f);
  u += 0x7FFFu + ((u >> 16) & 1u);   // round-to-nearest-even
  return (short)(u >> 16);
}
__device__ inline float bf16_to_f32(short s) {
  unsigned u = ((unsigned)(unsigned short)s) << 16;
  return __builtin_bit_cast(float, u);
}

// table[v][h] = b_h[h] + sum_e W_emb[v][e] * W_xh[e][h]   (115 x 512)
__global__ void prep_table(const float* __restrict__ Wemb, const float* __restrict__ Wxh,
                           const float* __restrict__ bh, float* __restrict__ Txh) {
  int v = blockIdx.x;
  int h = threadIdx.x;
  float s = bh[h];
  const float* we = Wemb + v * E_;
#pragma unroll 8
  for (int e = 0; e < E_; ++e) s += we[e] * Wxh[e * H_ + h];
  Txh[v * H_ + h] = s;
}

// Wt[n][k] = bf16(W_hh[k][n])  (transpose so MFMA B-frag reads 8 contiguous k)
__global__ void prep_wt(const float* __restrict__ Whh, short* __restrict__ Wt) {
  __shared__ float tile[64][65];
  int k0 = blockIdx.x * 64, n0 = blockIdx.y * 64;
  int x = threadIdx.x, y = threadIdx.y;
  for (int kk = y; kk < 64; kk += 8)
    tile[kk][x] = Whh[(k0 + kk) * H_ + n0 + x];
  __syncthreads();
  for (int nn = y; nn < 64; nn += 8)
    Wt[(n0 + nn) * H_ + k0 + x] = f32_to_bf16(tile[x][nn]);
}

__device__ inline float tanh_fast(float x) {
  float e = __expf(-2.0f * fabsf(x));
  float t = (1.0f - e) / (1.0f + e);
  return copysignf(t, x);
}

// 64 blocks x 512 threads (8 waves). Block owns batch rows [blockIdx*16, +16).
// Wave w owns output cols [w*64, w*64+64) = 4 n-frags of 16.
// LDS A-frag buffers hold h_t (hi/lo bf16) in MFMA A-fragment layout:
//   element (m, k):  Ahi[(k>>5)*512 + (m + 16*((k>>3)&3))*8 + (k&7)]
// so the K-loop read is a clean per-lane ds_read_b128: Ahi[kc*512 + lane*8 .. +8].
__global__ __launch_bounds__(512, 2) void rnn_main(
    const int* __restrict__ X, const float* __restrict__ Txh,
    const short* __restrict__ Wt, const float* __restrict__ Why,
    const float* __restrict__ by, float* __restrict__ Hfin,
    float* __restrict__ out) {
  __shared__ short Ahi[16 * H_];
  __shared__ short Alo[16 * H_];
  __shared__ int sX[16];

  const int tid = threadIdx.x;
  const int lane = tid & 63;
  const int ncol0 = (tid >> 6) * 64;   // wave's column base
  const int r0 = blockIdx.x * 16;      // batch row base
  const int lm = lane & 15;
  const int lg = lane >> 4;

  // h0 = 0
  for (int i = tid; i < 16 * H_; i += 512) { Ahi[i] = 0; Alo[i] = 0; }

  // W B-frag base: lane reads Wt[(ncol0 + f*16 + lm)][kc*32 + lg*8 .. +8]
  const int wbase = (ncol0 + lm) * H_ + lg * 8;

  for (int t = 0; t < T_; ++t) {
    if (tid < 16) sX[tid] = X[(r0 + tid) * T_ + t];
    __syncthreads();  // B1: prev-step A-frag writes + sX visible

    // prefetch xh for this lane's 16 output elems (latency hides under K-loop)
    float xh[4][4];
#pragma unroll
    for (int r = 0; r < 4; ++r) {
      const float* tp = Txh + sX[lg * 4 + r] * H_;
#pragma unroll
      for (int f = 0; f < 4; ++f) xh[f][r] = tp[ncol0 + f * 16 + lm];
    }

    f32x4 acc[4] = {{0.f,0.f,0.f,0.f},{0.f,0.f,0.f,0.f},{0.f,0.f,0.f,0.f},{0.f,0.f,0.f,0.f}};

#pragma unroll 2
    for (int kc = 0; kc < 16; ++kc) {
      short8 ah = *(const short8*)(Ahi + kc * 512 + lane * 8);
      short8 al = *(const short8*)(Alo + kc * 512 + lane * 8);
      short8 w0 = *(const short8*)(Wt + wbase + 0 * 16 * H_ + kc * 32);
      short8 w1 = *(const short8*)(Wt + wbase + 1 * 16 * H_ + kc * 32);
      short8 w2 = *(const short8*)(Wt + wbase + 2 * 16 * H_ + kc * 32);
      short8 w3 = *(const short8*)(Wt + wbase + 3 * 16 * H_ + kc * 32);
      acc[0] = __builtin_amdgcn_mfma_f32_16x16x32_bf16(ah, w0, acc[0], 0, 0, 0);
      acc[1] = __builtin_amdgcn_mfma_f32_16x16x32_bf16(ah, w1, acc[1], 0, 0, 0);
      acc[2] = __builtin_amdgcn_mfma_f32_16x16x32_bf16(ah, w2, acc[2], 0, 0, 0);
      acc[3] = __builtin_amdgcn_mfma_f32_16x16x32_bf16(ah, w3, acc[3], 0, 0, 0);
      acc[0] = __builtin_amdgcn_mfma_f32_16x16x32_bf16(al, w0, acc[0], 0, 0, 0);
      acc[1] = __builtin_amdgcn_mfma_f32_16x16x32_bf16(al, w1, acc[1], 0, 0, 0);
      acc[2] = __builtin_amdgcn_mfma_f32_16x16x32_bf16(al, w2, acc[2], 0, 0, 0);
      acc[3] = __builtin_amdgcn_mfma_f32_16x16x32_bf16(al, w3, acc[3], 0, 0, 0);
    }

    __syncthreads();  // B3: all waves done reading A-frags; safe to overwrite

    // epilogue: add xh, tanh, split hi/lo, scatter into A-frag layout
#pragma unroll
    for (int f = 0; f < 4; ++f) {
      int n = ncol0 + f * 16 + lm;
      int kc = n >> 5;
      int base = kc * 512 + 16 * ((n >> 3) & 3) * 8 + (n & 7);
#pragma unroll
      for (int r = 0; r < 4; ++r) {
        int m = lg * 4 + r;  // C/D layout: row = (lane>>4)*4 + reg
        float a = acc[f][r] + xh[f][r];
        float hv = tanh_fast(a);
        short hi = f32_to_bf16(hv);
        short lo = f32_to_bf16(hv - bf16_to_f32(hi));
        Ahi[base + m * 8] = hi;
        Alo[base + m * 8] = lo;
        if (t == T_ - 1) Hfin[(r0 + m) * H_ + n] = hv;
      }
    }
  }

  __syncthreads();  // Hfin stores drained (vmcnt 0 at barrier)

  // logits = h_T @ W_hy + b_y for this block's 16 rows
  for (int idx = tid; idx < 16 * V_; idx += 512) {
    int m = idx / V_, v = idx - m * V_;
    const float* hp = Hfin + (r0 + m) * H_;
    float s = by[v];
#pragma unroll 8
    for (int k = 0; k < H_; ++k) s += hp[k] * Why[k * V_ + v];
    out[(r0 + m) * V_ + v] = s;
  }
}

extern "C" void kernel_launch(void* const* d_in, const int* in_sizes, int n_in,
                              void* d_out, int out_size, void* d_ws, size_t ws_size,
                              hipStream_t stream) {
  const int* X = (const int*)d_in[0];         // [1024,256] int32
  const float* Wemb = (const float*)d_in[1];  // [115,128]
  const float* Wxh = (const float*)d_in[2];   // [128,512]
  const float* Whh = (const float*)d_in[3];   // [512,512]
  const float* bh = (const float*)d_in[4];    // [512]
  const float* Why = (const float*)d_in[5];   // [512,115]
  const float* by = (const float*)d_in[6];    // [115]
  float* out = (float*)d_out;                 // [1024,115]

  char* ws = (char*)d_ws;
  float* Txh = (float*)ws;                    // 115*512*4  = 235,520 B
  short* Wt = (short*)(ws + 256 * 1024);      // 512*512*2  = 524,288 B
  float* Hfin = (float*)(ws + 1024 * 1024);   // 1024*512*4 = 2 MB

  prep_table<<<dim3(V_), dim3(H_), 0, stream>>>(Wemb, Wxh, bh, Txh);
  prep_wt<<<dim3(8, 8), dim3(64, 8), 0, stream>>>(Whh, Wt);
  rnn_main<<<dim3(64), dim3(512), 0, stream>>>(X, Txh, Wt, Why, by, Hfin, out);
}

// Round 2
// 1912.983 us; speedup vs baseline: 2.1295x; 2.1295x over previous
//
#include <hip/hip_runtime.h>

// RNN on MI355X: h_{t+1} = tanh(table[X[:,t]] + h_t @ W_hh), T=256, B=1024, H=512.
// Round 2: kill the W-stream latency wall.
//  - 64 blocks x 512 thr (8 waves), block owns 16 batch rows; wave owns 64 cols.
//  - Wave's W slice = 64 cols x 512 k bf16 = 64KB = 16 chunks of k=32.
//    Chunks 0..8 (144 VGPRs) live PERMANENTLY in registers (W is t-invariant).
//    Chunks 9..15 (224KB/CU/step) streamed from L2 with 2-buffer issue-ahead
//    pipeline that crosses the step barriers (raw s_barrier + lgkmcnt only,
//    no vmcnt(0) drain -> loads stay in flight through the epilogue).
//  - bf16 MFMA 16x16x32, 2-term h split (hi+lo) for accuracy (absmax 0.0156).

typedef __attribute__((ext_vector_type(8))) short short8;
typedef __attribute__((ext_vector_type(4))) float f32x4;

#define B_ 1024
#define T_ 256
#define E_ 128
#define H_ 512
#define V_ 115
#define KHOLD 9   // chunks 0..8 register-resident; 9..15 streamed

__device__ inline short f32_to_bf16(float f) {
  unsigned u = __builtin_bit_cast(unsigned, f);
  u += 0x7FFFu + ((u >> 16) & 1u);   // round-to-nearest-even
  return (short)(u >> 16);
}
__device__ inline float bf16_to_f32(short s) {
  unsigned u = ((unsigned)(unsigned short)s) << 16;
  return __builtin_bit_cast(float, u);
}

__device__ inline float tanh_fast(float x) {
  float e = __expf(-2.0f * fabsf(x));
  float t = (1.0f - e) / (1.0f + e);
  return copysignf(t, x);
}

// Raw barrier: waits LDS ops only; global loads stay in flight (the point).
__device__ inline void sync_lgkm() {
  asm volatile("s_waitcnt lgkmcnt(0)" ::: "memory");
  __builtin_amdgcn_s_barrier();
}

// table[v][h] = b_h[h] + sum_e W_emb[v][e] * W_xh[e][h]   (115 x 512)
__global__ void prep_table(const float* __restrict__ Wemb, const float* __restrict__ Wxh,
                           const float* __restrict__ bh, float* __restrict__ Txh) {
  int v = blockIdx.x;
  int h = threadIdx.x;
  float s = bh[h];
  const float* we = Wemb + v * E_;
#pragma unroll 8
  for (int e = 0; e < E_; ++e) s += we[e] * Wxh[e * H_ + h];
  Txh[v * H_ + h] = s;
}

// Wt[n][k] = bf16(W_hh[k][n])
__global__ void prep_wt(const float* __restrict__ Whh, short* __restrict__ Wt) {
  __shared__ float tile[64][65];
  int k0 = blockIdx.x * 64, n0 = blockIdx.y * 64;
  int x = threadIdx.x, y = threadIdx.y;
  for (int kk = y; kk < 64; kk += 8)
    tile[kk][x] = Whh[(k0 + kk) * H_ + n0 + x];
  __syncthreads();
  for (int nn = y; nn < 64; nn += 8)
    Wt[(n0 + nn) * H_ + k0 + x] = f32_to_bf16(tile[x][nn]);
}

#define WLOAD(dst, kc_)                                              \
  dst[0] = *(const short8*)(Wt + wbase + 0 * 16 * H_ + (kc_) * 32);  \
  dst[1] = *(const short8*)(Wt + wbase + 1 * 16 * H_ + (kc_) * 32);  \
  dst[2] = *(const short8*)(Wt + wbase + 2 * 16 * H_ + (kc_) * 32);  \
  dst[3] = *(const short8*)(Wt + wbase + 3 * 16 * H_ + (kc_) * 32);

#define CHUNK(wv, kc_) {                                                   \
  short8 ah = *(const short8*)(Ahi + (kc_) * 512 + lane * 8);              \
  short8 al = *(const short8*)(Alo + (kc_) * 512 + lane * 8);              \
  acc[0] = __builtin_amdgcn_mfma_f32_16x16x32_bf16(ah, wv[0], acc[0], 0, 0, 0); \
  acc[1] = __builtin_amdgcn_mfma_f32_16x16x32_bf16(ah, wv[1], acc[1], 0, 0, 0); \
  acc[2] = __builtin_amdgcn_mfma_f32_16x16x32_bf16(ah, wv[2], acc[2], 0, 0, 0); \
  acc[3] = __builtin_amdgcn_mfma_f32_16x16x32_bf16(ah, wv[3], acc[3], 0, 0, 0); \
  acc[0] = __builtin_amdgcn_mfma_f32_16x16x32_bf16(al, wv[0], acc[0], 0, 0, 0); \
  acc[1] = __builtin_amdgcn_mfma_f32_16x16x32_bf16(al, wv[1], acc[1], 0, 0, 0); \
  acc[2] = __builtin_amdgcn_mfma_f32_16x16x32_bf16(al, wv[2], acc[2], 0, 0, 0); \
  acc[3] = __builtin_amdgcn_mfma_f32_16x16x32_bf16(al, wv[3], acc[3], 0, 0, 0); }

__global__ __launch_bounds__(512, 2) void rnn_main(
    const int* __restrict__ X, const float* __restrict__ Txh,
    const short* __restrict__ Wt, const float* __restrict__ Why,
    const float* __restrict__ by, float* __restrict__ Hfin,
    float* __restrict__ out) {
  __shared__ short Ahi[16 * H_];   // h_t hi bf16, MFMA A-frag layout
  __shared__ short Alo[16 * H_];   // h_t lo bf16
  __shared__ int sXall[16 * T_];   // this block's X rows, staged once

  const int tid = threadIdx.x;
  const int lane = tid & 63;
  const int ncol0 = (tid >> 6) * 64;
  const int r0 = blockIdx.x * 16;
  const int lm = lane & 15;
  const int lg = lane >> 4;

  for (int i = tid; i < 16 * H_; i += 512) { Ahi[i] = 0; Alo[i] = 0; }
  for (int i = tid; i < 16 * T_; i += 512)
    sXall[i] = X[(r0 + (i >> 8)) * T_ + (i & 255)];

  const int wbase = (ncol0 + lm) * H_ + lg * 8;

  // Register-resident W: chunks 0..KHOLD-1 (loop-invariant)
  short8 wreg[KHOLD][4];
#pragma unroll
  for (int kc = 0; kc < KHOLD; ++kc) { WLOAD(wreg[kc], kc) }

  // Prime the streaming double-buffer: wa <- chunk 9, wb <- chunk 10
  short8 wa[4], wb[4];
  WLOAD(wa, 9)
  WLOAD(wb, 10)

  __syncthreads();

  for (int t = 0; t < T_; ++t) {
    // xh gathers for this step: issued now, consumed in epilogue (hidden)
    float xh[4][4];
#pragma unroll
    for (int r = 0; r < 4; ++r) {
      int vx = sXall[(lg * 4 + r) * T_ + t];
      const float* tp = Txh + vx * H_ + ncol0 + lm;
#pragma unroll
      for (int f = 0; f < 4; ++f) xh[f][r] = tp[f * 16];
    }

    f32x4 acc[4] = {{0.f,0.f,0.f,0.f},{0.f,0.f,0.f,0.f},{0.f,0.f,0.f,0.f},{0.f,0.f,0.f,0.f}};

    // Register-held chunks (no memory traffic for W)
#pragma unroll
    for (int kc = 0; kc < KHOLD; ++kc) CHUNK(wreg[kc], kc)

    // Streamed chunks 9..15: consume, then issue 2 ahead; last two issues
    // prime NEXT step's wa/wb (loads fly across the barriers below).
    CHUNK(wa, 9)   WLOAD(wa, 11)
    CHUNK(wb, 10)  WLOAD(wb, 12)
    CHUNK(wa, 11)  WLOAD(wa, 13)
    CHUNK(wb, 12)  WLOAD(wb, 14)
    CHUNK(wa, 13)  WLOAD(wa, 15)
    CHUNK(wb, 14)  WLOAD(wb, 10)   // next step's wb
    CHUNK(wa, 15)  WLOAD(wa, 9)    // next step's wa

    sync_lgkm();  // B3: all waves' A-frag reads complete; safe to overwrite

    // epilogue: add xh, tanh, hi/lo split, scatter into A-frag layout
#pragma unroll
    for (int f = 0; f < 4; ++f) {
      int n = ncol0 + f * 16 + lm;
      int base = (n >> 5) * 512 + ((n >> 3) & 3) * 128 + (n & 7);
#pragma unroll
      for (int r = 0; r < 4; ++r) {
        int m = lg * 4 + r;
        float hv = tanh_fast(acc[f][r] + xh[f][r]);
        short hi = f32_to_bf16(hv);
        short lo = f32_to_bf16(hv - bf16_to_f32(hi));
        Ahi[base + m * 8] = hi;
        Alo[base + m * 8] = lo;
        if (t == T_ - 1) Hfin[(r0 + m) * H_ + n] = hv;
      }
    }

    sync_lgkm();  // B1: A-frag writes visible for next step
  }

  __syncthreads();  // full drain (Hfin global stores) before logits

  // logits = h_T @ W_hy + b_y for this block's 16 rows
  for (int idx = tid; idx < 16 * V_; idx += 512) {
    int m = idx / V_, v = idx - m * V_;
    const float* hp = Hfin + (r0 + m) * H_;
    float s = by[v];
#pragma unroll 8
    for (int k = 0; k < H_; ++k) s += hp[k] * Why[k * V_ + v];
    out[(r0 + m) * V_ + v] = s;
  }
}

extern "C" void kernel_launch(void* const* d_in, const int* in_sizes, int n_in,
                              void* d_out, int out_size, void* d_ws, size_t ws_size,
                              hipStream_t stream) {
  const int* X = (const int*)d_in[0];         // [1024,256] int32
  const float* Wemb = (const float*)d_in[1];  // [115,128]
  const float* Wxh = (const float*)d_in[2];   // [128,512]
  const float* Whh = (const float*)d_in[3];   // [512,512]
  const float* bh = (const float*)d_in[4];    // [512]
  const float* Why = (const float*)d_in[5];   // [512,115]
  const float* by = (const float*)d_in[6];    // [115]
  float* out = (float*)d_out;                 // [1024,115]

  char* ws = (char*)d_ws;
  float* Txh = (float*)ws;                    // 115*512*4  = 235,520 B
  short* Wt = (short*)(ws + 256 * 1024);      // 512*512*2  = 524,288 B
  float* Hfin = (float*)(ws + 1024 * 1024);   // 1024*512*4 = 2 MB

  prep_table<<<dim3(V_), dim3(H_), 0, stream>>>(Wemb, Wxh, bh, Txh);
  prep_wt<<<dim3(8, 8), dim3(64, 8), 0, stream>>>(Whh, Wt);
  rnn_main<<<dim3(64), dim3(512), 0, stream>>>(X, Txh, Wt, Why, by, Hfin, out);
}

// Round 3
// 1827.656 us; speedup vs baseline: 2.2289x; 1.0467x over previous
//
#include <hip/hip_runtime.h>

// RNN on MI355X: h_{t+1} = tanh(table[X[:,t]] + h_t @ W_hh), T=256, B=1024, H=512.
// Round 3: force W register-residency (round 2's plan was silently rematerialized:
// VGPR_Count=128 proved the compiler reloaded "resident" chunks every step).
//  - 64 blocks x 512 thr (8 waves); block owns 16 batch rows; wave owns 64 cols.
//  - Wave W slice = 16 chunk-sets (k=32 each) x 4 frags x 16B/lane.
//    Sets 0..8: VGPR-resident, loaded once, pinned via asm launder (no remat).
//    Sets 9..15: streamed from L2, 2 rotating buffers, cross-barrier prefetch.
//  - Wt2 layout: each (colblock,set,frag) is a contiguous 1KB wave-load.
//  - bf16 MFMA 16x16x32, 2-term h split (hi+lo): absmax 0.015625.

typedef __attribute__((ext_vector_type(8))) short short8;
typedef __attribute__((ext_vector_type(4))) float f32x4;

#define B_ 1024
#define T_ 256
#define E_ 128
#define H_ 512
#define V_ 115
#define KHOLD 9

__device__ inline short f32_to_bf16(float f) {
  unsigned u = __builtin_bit_cast(unsigned, f);
  u += 0x7FFFu + ((u >> 16) & 1u);
  return (short)(u >> 16);
}
__device__ inline float bf16_to_f32(short s) {
  unsigned u = ((unsigned)(unsigned short)s) << 16;
  return __builtin_bit_cast(float, u);
}
__device__ inline float tanh_fast(float x) {
  float e = __expf(-2.0f * fabsf(x));
  float t = (1.0f - e) / (1.0f + e);
  return copysignf(t, x);
}
// Pin a 4-VGPR vector: value becomes asm output -> rematerialization illegal.
__device__ __forceinline__ void pin(f32x4& v) { asm volatile("" : "+v"(v)); }

// Barrier that does NOT drain vmcnt: prefetched W loads stay in flight.
__device__ __forceinline__ void sync_lgkm() {
  asm volatile("s_waitcnt lgkmcnt(0)" ::: "memory");
  __builtin_amdgcn_s_barrier();
}

// table[v][h] = b_h[h] + sum_e W_emb[v][e] * W_xh[e][h]   (115 x 512)
__global__ void prep_table(const float* __restrict__ Wemb, const float* __restrict__ Wxh,
                           const float* __restrict__ bh, float* __restrict__ Txh) {
  int v = blockIdx.x;
  int h = threadIdx.x;
  float s = bh[h];
  const float* we = Wemb + v * E_;
#pragma unroll 8
  for (int e = 0; e < E_; ++e) s += we[e] * Wxh[e * H_ + h];
  Txh[v * H_ + h] = s;
}

// Wt2 layout: for col-block nb (16 cols), set kc (k=32):
//   1KB block at ((nb*16+kc)*64)*8 shorts; lane L holds row nb*16+(L&15),
//   k = kc*32 + (L>>4)*8 .. +8  ->  B-frag load = contiguous lane*16B.
__global__ void prep_wt2(const float* __restrict__ Whh, short* __restrict__ Wt2) {
  int idx = blockIdx.x * 256 + threadIdx.x;  // 512*512
  int k = idx >> 9, n = idx & 511;
  float w = Whh[k * H_ + n];
  int nb = n >> 4, lm = n & 15, kc = k >> 5, lg = (k >> 3) & 3, kk = k & 7;
  Wt2[((((nb * 16 + kc) * 4 + lg) * 16 + lm) << 3) + kk] = f32_to_bf16(w);
}

// frag f, set kc for wave with col-block base nb0: contiguous 1KB
#define WADDR(f, kc_) (Wt2 + ((((nb0 + (f)) * 16 + (kc_)) << 6) + lane) * 8)

#define WLOADV(dst, kc_)                                             \
  dst[0] = *(const f32x4*)WADDR(0, kc_);                             \
  dst[1] = *(const f32x4*)WADDR(1, kc_);                             \
  dst[2] = *(const f32x4*)WADDR(2, kc_);                             \
  dst[3] = *(const f32x4*)WADDR(3, kc_);

#define CHUNKV(wv, kc_) {                                                  \
  short8 ah = *(const short8*)(Ahi + (kc_) * 512 + lane * 8);              \
  short8 al = *(const short8*)(Alo + (kc_) * 512 + lane * 8);              \
  short8 b0 = __builtin_bit_cast(short8, wv[0]);                           \
  short8 b1 = __builtin_bit_cast(short8, wv[1]);                           \
  short8 b2 = __builtin_bit_cast(short8, wv[2]);                           \
  short8 b3 = __builtin_bit_cast(short8, wv[3]);                           \
  acc[0] = __builtin_amdgcn_mfma_f32_16x16x32_bf16(ah, b0, acc[0], 0, 0, 0); \
  acc[1] = __builtin_amdgcn_mfma_f32_16x16x32_bf16(ah, b1, acc[1], 0, 0, 0); \
  acc[2] = __builtin_amdgcn_mfma_f32_16x16x32_bf16(ah, b2, acc[2], 0, 0, 0); \
  acc[3] = __builtin_amdgcn_mfma_f32_16x16x32_bf16(ah, b3, acc[3], 0, 0, 0); \
  acc[0] = __builtin_amdgcn_mfma_f32_16x16x32_bf16(al, b0, acc[0], 0, 0, 0); \
  acc[1] = __builtin_amdgcn_mfma_f32_16x16x32_bf16(al, b1, acc[1], 0, 0, 0); \
  acc[2] = __builtin_amdgcn_mfma_f32_16x16x32_bf16(al, b2, acc[2], 0, 0, 0); \
  acc[3] = __builtin_amdgcn_mfma_f32_16x16x32_bf16(al, b3, acc[3], 0, 0, 0); }

__global__ __launch_bounds__(512, 2) __attribute__((amdgpu_waves_per_eu(2, 2)))
void rnn_main(
    const int* __restrict__ X, const float* __restrict__ Txh,
    const short* __restrict__ Wt2, const float* __restrict__ Why,
    const float* __restrict__ by, float* __restrict__ Hfin,
    float* __restrict__ out) {
  __shared__ short Ahi[16 * H_];   // h_t hi bf16, MFMA A-frag layout
  __shared__ short Alo[16 * H_];   // h_t lo bf16
  __shared__ int sXall[16 * T_];

  const int tid = threadIdx.x;
  const int lane = tid & 63;
  const int nb0 = (tid >> 6) * 4;  // wave's col-block base (4 frags of 16)
  const int ncol0 = nb0 * 16;
  const int r0 = blockIdx.x * 16;
  const int lm = lane & 15;
  const int lg = lane >> 4;

  for (int i = tid; i < 16 * H_; i += 512) { Ahi[i] = 0; Alo[i] = 0; }
  for (int i = tid; i < 16 * T_; i += 512)
    sXall[i] = X[(r0 + (i >> 8)) * T_ + (i & 255)];

  // Register-resident W: sets 0..KHOLD-1, loaded once, PINNED (no remat).
  f32x4 wreg[KHOLD][4];
#pragma unroll
  for (int kc = 0; kc < KHOLD; ++kc) { WLOADV(wreg[kc], kc) }
#pragma unroll
  for (int kc = 0; kc < KHOLD; ++kc) {
    pin(wreg[kc][0]); pin(wreg[kc][1]); pin(wreg[kc][2]); pin(wreg[kc][3]);
  }

  // Prime stream double-buffer: wa <- set 9, wb <- set 10
  f32x4 wa[4], wb[4];
  WLOADV(wa, 9)
  WLOADV(wb, 10)

  __syncthreads();

  for (int t = 0; t < T_; ++t) {
    f32x4 acc[4] = {{0.f,0.f,0.f,0.f},{0.f,0.f,0.f,0.f},{0.f,0.f,0.f,0.f},{0.f,0.f,0.f,0.f}};

    // Resident sets: zero W memory traffic.
#pragma unroll
    for (int kc = 0; kc < KHOLD; ++kc) CHUNKV(wreg[kc], kc)

    // xh gather mid-loop: ~2000 cyc of stream phase hides the L2 latency.
    float xh[4][4];
#pragma unroll
    for (int r = 0; r < 4; ++r) {
      int vx = sXall[(lg * 4 + r) * T_ + t];
      const float* tp = Txh + vx * H_ + ncol0 + lm;
#pragma unroll
      for (int f = 0; f < 4; ++f) xh[f][r] = tp[f * 16];
    }

    // Streamed sets 9..15; last two issues prime NEXT step's buffers and
    // fly across the barriers (sync_lgkm never drains vmcnt).
    CHUNKV(wa, 9)   WLOADV(wa, 11)
    CHUNKV(wb, 10)  WLOADV(wb, 12)
    CHUNKV(wa, 11)  WLOADV(wa, 13)
    CHUNKV(wb, 12)  WLOADV(wb, 14)
    CHUNKV(wa, 13)  WLOADV(wa, 15)
    CHUNKV(wb, 14)  WLOADV(wb, 10)   // next step's wb
    CHUNKV(wa, 15)  WLOADV(wa, 9)    // next step's wa

    sync_lgkm();  // all waves' A-frag reads done; safe to overwrite

#pragma unroll
    for (int f = 0; f < 4; ++f) {
      int n = ncol0 + f * 16 + lm;
      int base = (n >> 5) * 512 + ((n >> 3) & 3) * 128 + (n & 7);
#pragma unroll
      for (int r = 0; r < 4; ++r) {
        int m = lg * 4 + r;
        float hv = tanh_fast(acc[f][r] + xh[f][r]);
        short hi = f32_to_bf16(hv);
        short lo = f32_to_bf16(hv - bf16_to_f32(hi));
        Ahi[base + m * 8] = hi;
        Alo[base + m * 8] = lo;
        if (t == T_ - 1) Hfin[(r0 + m) * H_ + n] = hv;
      }
    }

    sync_lgkm();  // A-frag writes visible for next step
  }

  __syncthreads();

  // logits = h_T @ W_hy + b_y for this block's 16 rows
  for (int idx = tid; idx < 16 * V_; idx += 512) {
    int m = idx / V_, v = idx - m * V_;
    const float* hp = Hfin + (r0 + m) * H_;
    float s = by[v];
#pragma unroll 8
    for (int k = 0; k < H_; ++k) s += hp[k] * Why[k * V_ + v];
    out[(r0 + m) * V_ + v] = s;
  }
}

extern "C" void kernel_launch(void* const* d_in, const int* in_sizes, int n_in,
                              void* d_out, int out_size, void* d_ws, size_t ws_size,
                              hipStream_t stream) {
  const int* X = (const int*)d_in[0];
  const float* Wemb = (const float*)d_in[1];
  const float* Wxh = (const float*)d_in[2];
  const float* Whh = (const float*)d_in[3];
  const float* bh = (const float*)d_in[4];
  const float* Why = (const float*)d_in[5];
  const float* by = (const float*)d_in[6];
  float* out = (float*)d_out;

  char* ws = (char*)d_ws;
  float* Txh = (float*)ws;                    // 235,520 B
  short* Wt2 = (short*)(ws + 256 * 1024);     // 524,288 B
  float* Hfin = (float*)(ws + 1024 * 1024);   // 2 MB

  prep_table<<<dim3(V_), dim3(H_), 0, stream>>>(Wemb, Wxh, bh, Txh);
  prep_wt2<<<dim3(1024), dim3(256), 0, stream>>>(Whh, Wt2);
  rnn_main<<<dim3(64), dim3(512), 0, stream>>>(X, Txh, Wt2, Why, by, Hfin, out);
}